// Round 11
// baseline (100.511 us; speedup 1.0000x reference)
//
#include <hip/hip_runtime.h>

// B=16384, DIM=64, 8 coupling steps, H=8, D2=32.
// y = J^{-1} g applied analytically (triangular coupling blocks -> MLP JVPs);
// intermediate states recovered by inverting the flow from z = phi(x).
//
// R11 = R9 MFMA formulation at HALF elements per wave for 2x occupancy.
// R9/R10 post-mortem: at 1 wave/SIMD the kernel is ~95% stall (2850 cyc/pair
// vs ~150 cyc issue work); every pipe <10% busy. 16 elem/wave is forced by
// the 16x16 MFMA shape -> 1024 waves. Fix: 8 elements/wave, MFMA columns n
// and n^8 carry DUPLICATE elements (lanes n, n^8 compute identical state
// trajectories; lanes n<8 write out). Per-wave work unchanged; waves double
// to 2048 = 2/SIMD, 8/CU. LDS 43 KiB -> 2 blocks/CU.
//   L1: mfma_f32_16x16x32_f16  A=[W0t;W0s](16x32)  B=V(32x16)
//   L2: mfma_f32_16x16x16f16   A=blockdiag(W1t,W1s) B=H1
//   L3: 4x mfma_f32_16x16x16f16, W2 rows pre-permuted to state layout.
// Layout identity (gfx950, verified m89): D (col=lane&15,row=4q+reg) ==
// B-operand (n=lane&15,k=4q+j) for K=16 -> tanh(D)->pack per-lane, zero
// cross-lane ops. JVP shares all A-fragments.

namespace {

typedef __fp16 f16x2 __attribute__((ext_vector_type(2)));
typedef __fp16 v4h __attribute__((ext_vector_type(4)));
typedef __fp16 v8h __attribute__((ext_vector_type(8)));
typedef float f32x4 __attribute__((ext_vector_type(4)));

constexpr int NB = 16384;

__device__ __forceinline__ float frcp(float x) { return __builtin_amdgcn_rcpf(x); }
__device__ __forceinline__ float ftanh(float x) {
  float e = __expf(2.f * x);
  return 1.f - 2.f * frcp(e + 1.f);
}
__device__ __forceinline__ f16x2 pk(float a, float b) {
  return __builtin_amdgcn_cvt_pkrtz(a, b);
}

union U8 { v8h v; f16x2 h[4]; };
union U4 { v4h v; f16x2 h[2]; };

// net pair p (0..15): step i = p>>1, half = p&1 -> t-net base.
__device__ __forceinline__ int pbase(int p) {
  return ((p >> 1) << 2) + ((p & 1) << 1);
}

// Evaluate both nets of pair p at v (and JVP at u): t/s (+ut/us) per lane,
// local j=0..7 <-> state dims 8q+j.
template <bool JVP>
__device__ __forceinline__ void pair_apply(
    const f16x2* __restrict__ LW0, const f16x2* __restrict__ LW1,
    const f16x2* __restrict__ LW2, const float* __restrict__ LB0,
    const float* __restrict__ LB1, const float* __restrict__ LB2, int p,
    int n, int q, const float v[8], const float* __restrict__ u, float t8[8],
    float s8[8], float* __restrict__ ut8, float* __restrict__ us8) {
  v4h z4;
#pragma unroll
  for (int jj = 0; jj < 4; ++jj) z4[jj] = (__fp16)0.f;
  const f32x4 zc = {0.f, 0.f, 0.f, 0.f};

  U8 B;
  B.h[0] = pk(v[0], v[1]);
  B.h[1] = pk(v[2], v[3]);
  B.h[2] = pk(v[4], v[5]);
  B.h[3] = pk(v[6], v[7]);

  const v8h A0 = *(const v8h*)(LW0 + ((p * 64 + q * 16 + n) << 2));
  const f32x4 c0 = *(const f32x4*)(LB0 + p * 16 + q * 4);
  f32x4 d1 = __builtin_amdgcn_mfma_f32_16x16x32_f16(A0, B.v, c0, 0, 0, 0);
  float h1[4];
#pragma unroll
  for (int r = 0; r < 4; ++r) h1[r] = ftanh(d1[r]);
  U4 H1;
  H1.h[0] = pk(h1[0], h1[1]);
  H1.h[1] = pk(h1[2], h1[3]);

  const bool act1 = (n < 8) == (q < 2);
  v4h A1 = *(const v4h*)(LW1 + (p * 64 + ((n & 7) << 2) + ((q & 1) << 1) +
                                ((n >= 8) ? 32 : 0)));
  A1 = act1 ? A1 : z4;
  const f32x4 c1 = *(const f32x4*)(LB1 + p * 16 + q * 4);
  f32x4 d2 = __builtin_amdgcn_mfma_f32_16x16x16f16(A1, H1.v, c1, 0, 0, 0);
  float h2[4];
#pragma unroll
  for (int r = 0; r < 4; ++r) h2[r] = ftanh(d2[r]);
  U4 H2;
  H2.h[0] = pk(h2[0], h2[1]);
  H2.h[1] = pk(h2[2], h2[3]);

  U4 G2;
  if constexpr (JVP) {
    U8 Bu;
    Bu.h[0] = pk(u[0], u[1]);
    Bu.h[1] = pk(u[2], u[3]);
    Bu.h[2] = pk(u[4], u[5]);
    Bu.h[3] = pk(u[6], u[7]);
    f32x4 d1u = __builtin_amdgcn_mfma_f32_16x16x32_f16(A0, Bu.v, zc, 0, 0, 0);
    float g1[4];
#pragma unroll
    for (int r = 0; r < 4; ++r) g1[r] = (1.f - h1[r] * h1[r]) * d1u[r];
    U4 G1;
    G1.h[0] = pk(g1[0], g1[1]);
    G1.h[1] = pk(g1[2], g1[3]);
    f32x4 d2u = __builtin_amdgcn_mfma_f32_16x16x16f16(A1, G1.v, zc, 0, 0, 0);
    float g2[4];
#pragma unroll
    for (int r = 0; r < 4; ++r) g2[r] = (1.f - h2[r] * h2[r]) * d2u[r];
    G2.h[0] = pk(g2[0], g2[1]);
    G2.h[1] = pk(g2[2], g2[3]);
  }

  // L3: 4 blocks = {tX, tY, sX, sY}; W2 rows pre-permuted so lane q's D rows
  // 4q+r land at t/s local dims {r} (X) and {4+r} (Y).
#pragma unroll
  for (int b = 0; b < 4; ++b) {
    const bool act = (b < 2) == (q < 2);
    v4h Ab = *(const v4h*)(LW2 + (p * 256 + b * 64 + n * 4 + ((q & 1) << 1)));
    Ab = act ? Ab : z4;
    const f32x4 cb = *(const f32x4*)(LB2 + (p * 4 + b) * 16 + q * 4);
    f32x4 ob = __builtin_amdgcn_mfma_f32_16x16x16f16(Ab, H2.v, cb, 0, 0, 0);
    float* dst = (b < 2) ? t8 : s8;
    const int off = (b & 1) * 4;
#pragma unroll
    for (int r = 0; r < 4; ++r) dst[off + r] = ob[r];
    if constexpr (JVP) {
      f32x4 jb = __builtin_amdgcn_mfma_f32_16x16x16f16(Ab, G2.v, zc, 0, 0, 0);
      float* jdst = (b < 2) ? ut8 : us8;
#pragma unroll
      for (int r = 0; r < 4; ++r) jdst[off + r] = jb[r];
    }
  }
}

}  // namespace

// 256 threads = 4 waves = 32 elements/block (8/wave, duplicated into both
// column halves), grid 512 -> 2048 waves = 2/SIMD, 8 waves/CU.
// LDS 43 KiB -> 2 blocks/CU.
__global__ __launch_bounds__(256, 2) void nf_policy_kernel(
    const float* __restrict__ x, const float* __restrict__ xs,
    const float* __restrict__ gW0, const float* __restrict__ gb0,
    const float* __restrict__ gW1, const float* __restrict__ gb1,
    const float* __restrict__ gW2, const float* __restrict__ gb2,
    float* __restrict__ out) {
  __shared__ __align__(16) f16x2 LW0[4096];  // [16p][4q][16m][4w] A-frags L1
  __shared__ __align__(16) f16x2 LW1[1024];  // [16p][2half][8row][4kk]
  __shared__ __align__(16) f16x2 LW2[4096];  // [16p][4b][16m][4kk(2 used)]
  __shared__ __align__(16) float LB0[256];   // [16p][16m]
  __shared__ __align__(16) float LB1[256];   // [16p][16m]
  __shared__ __align__(16) float LB2[1024];  // [16p][4b][16m]

  const int tid = threadIdx.x;
  // ---- stage weights: fp32 global -> f16 LDS in MFMA A-fragment order ----
  for (int i = tid; i < 4096; i += 256) {  // LW0
    const int p = i >> 8, rem = i & 255, qq = rem >> 6, rem2 = rem & 63;
    const int mm = rem2 >> 2, w = rem2 & 3;
    const int net = pbase(p) + (mm >> 3);
    const int h = mm & 7, k0 = qq * 8 + w * 2;
    const float* src = gW0 + net * 256 + h * 32 + k0;
    LW0[i] = pk(src[0], src[1]);
  }
  for (int i = tid; i < 1024; i += 256) {  // LW1
    const int p = i >> 6, rem = i & 63, half = rem >> 5;
    const int row = (rem >> 2) & 7, kk = rem & 3;
    const int net = pbase(p) + half;
    const float* src = gW1 + net * 64 + row * 8 + kk * 2;
    LW1[i] = pk(src[0], src[1]);
  }
  for (int i = tid; i < 4096; i += 256) {  // LW2 (rows permuted)
    const int p = i >> 8, rem = i & 255, b = rem >> 6, rem2 = rem & 63;
    const int mm = rem2 >> 2, kk = rem2 & 3;
    const int net = pbase(p) + (b >> 1);
    const int d = 8 * (mm >> 2) + ((b & 1) << 2) + (mm & 3);
    const float* src = gW2 + net * 256 + d * 8 + kk * 2;
    LW2[i] = pk(src[0], src[1]);
  }
  for (int i = tid; i < 256; i += 256) {  // LB0/LB1
    const int p = i >> 4, mm = i & 15;
    const int net = pbase(p) + (mm >> 3);
    LB0[i] = gb0[net * 8 + (mm & 7)];
    LB1[i] = gb1[net * 8 + (mm & 7)];
  }
  for (int i = tid; i < 1024; i += 256) {  // LB2 (permuted like LW2 rows)
    const int p = i >> 6, b = (i >> 4) & 3, mm = i & 15;
    const int net = pbase(p) + (b >> 1);
    const int d = 8 * (mm >> 2) + ((b & 1) << 2) + (mm & 3);
    LB2[i] = gb2[net * 32 + d];
  }
  __syncthreads();

  const int lane = tid & 63;
  const int wv = tid >> 6;
  const int n = lane & 15;   // MFMA col / A row; cols n and n^8 duplicate
  const int q = lane >> 4;   // quad: owns state dims 8q..8q+7
  const int e = blockIdx.x * 32 + wv * 8 + (n & 7);  // 8 elements per wave

  float lo[8], up[8], av[8], bv[8];
  {
    const float* xe = x + (size_t)e * 64;
    const float* se = xs + (size_t)e * 64;
    const float4 a0 = *(const float4*)(xe + q * 8);
    const float4 a1 = *(const float4*)(xe + q * 8 + 4);
    const float4 u0 = *(const float4*)(xe + 32 + q * 8);
    const float4 u1 = *(const float4*)(xe + 32 + q * 8 + 4);
    const float4 p0 = *(const float4*)(se + q * 8);
    const float4 p1 = *(const float4*)(se + q * 8 + 4);
    const float4 r0 = *(const float4*)(se + 32 + q * 8);
    const float4 r1 = *(const float4*)(se + 32 + q * 8 + 4);
    lo[0] = a0.x; lo[1] = a0.y; lo[2] = a0.z; lo[3] = a0.w;
    lo[4] = a1.x; lo[5] = a1.y; lo[6] = a1.z; lo[7] = a1.w;
    up[0] = u0.x; up[1] = u0.y; up[2] = u0.z; up[3] = u0.w;
    up[4] = u1.x; up[5] = u1.y; up[6] = u1.z; up[7] = u1.w;
    av[0] = -2.f * (a0.x - p0.x); av[1] = -2.f * (a0.y - p0.y);
    av[2] = -2.f * (a0.z - p0.z); av[3] = -2.f * (a0.w - p0.w);
    av[4] = -2.f * (a1.x - p1.x); av[5] = -2.f * (a1.y - p1.y);
    av[6] = -2.f * (a1.z - p1.z); av[7] = -2.f * (a1.w - p1.w);
    bv[0] = -2.f * (u0.x - r0.x); bv[1] = -2.f * (u0.y - r0.y);
    bv[2] = -2.f * (u0.z - r0.z); bv[3] = -2.f * (u0.w - r0.w);
    bv[4] = -2.f * (u1.x - r1.x); bv[5] = -2.f * (u1.y - r1.y);
    bv[6] = -2.f * (u1.z - r1.z); bv[7] = -2.f * (u1.w - r1.w);
  }

  float t8[8], s8[8], ut8[8], us8[8];

  // ---------------- forward: z = phi(x) ----------------
#pragma unroll 1
  for (int i = 0; i < 8; ++i) {
    pair_apply<false>(LW0, LW1, LW2, LB0, LB1, LB2, 2 * i, n, q, lo, nullptr,
                      t8, s8, nullptr, nullptr);
#pragma unroll
    for (int j = 0; j < 8; ++j) up[j] = fmaf(up[j], __expf(s8[j]), t8[j]);
    pair_apply<false>(LW0, LW1, LW2, LB0, LB1, LB2, 2 * i + 1, n, q, up,
                      nullptr, t8, s8, nullptr, nullptr);
#pragma unroll
    for (int j = 0; j < 8; ++j) lo[j] = fmaf(lo[j], __expf(s8[j]), t8[j]);
  }

  // ------------- backward: y = J^{-1} g, inverting the flow -------------
#pragma unroll 1
  for (int i = 7; i >= 0; --i) {
    // T2^{-1}: eval t2/s2 at up', JVP at bv
    pair_apply<true>(LW0, LW1, LW2, LB0, LB1, LB2, 2 * i + 1, n, q, up, bv,
                     t8, s8, ut8, us8);
#pragma unroll
    for (int j = 0; j < 8; ++j) {
      const float esi = __expf(-s8[j]);
      const float d = lo[j] - t8[j];
      lo[j] = d * esi;
      av[j] = (av[j] - ut8[j] - d * us8[j]) * esi;
    }
    // T1^{-1}: eval t1/s1 at lo (pre-step), JVP at av (updated)
    pair_apply<true>(LW0, LW1, LW2, LB0, LB1, LB2, 2 * i, n, q, lo, av, t8,
                     s8, ut8, us8);
#pragma unroll
    for (int j = 0; j < 8; ++j) {
      const float esi = __expf(-s8[j]);
      const float d = up[j] - t8[j];
      up[j] = d * esi;
      bv[j] = (bv[j] - ut8[j] - d * us8[j]) * esi;
    }
  }

  if (n < 8) {  // lanes n>=8 are duplicates of n-8
    float* oe = out + (size_t)e * 64;
    float4 v;
    v.x = av[0]; v.y = av[1]; v.z = av[2]; v.w = av[3];
    *(float4*)(oe + q * 8) = v;
    v.x = av[4]; v.y = av[5]; v.z = av[6]; v.w = av[7];
    *(float4*)(oe + q * 8 + 4) = v;
    v.x = bv[0]; v.y = bv[1]; v.z = bv[2]; v.w = bv[3];
    *(float4*)(oe + 32 + q * 8) = v;
    v.x = bv[4]; v.y = bv[5]; v.z = bv[6]; v.w = bv[7];
    *(float4*)(oe + 32 + q * 8 + 4) = v;
  }
}

extern "C" void kernel_launch(void* const* d_in, const int* in_sizes, int n_in,
                              void* d_out, int out_size, void* d_ws,
                              size_t ws_size, hipStream_t stream) {
  const float* x  = (const float*)d_in[0];
  const float* xs = (const float*)d_in[1];
  const float* W0 = (const float*)d_in[2];
  const float* b0 = (const float*)d_in[3];
  const float* W1 = (const float*)d_in[4];
  const float* b1 = (const float*)d_in[5];
  const float* W2 = (const float*)d_in[6];
  const float* b2 = (const float*)d_in[7];
  float* out = (float*)d_out;

  dim3 grid(NB / 32);  // 512 blocks, 32 elements each (8 per wave)
  dim3 block(256);
  nf_policy_kernel<<<grid, block, 0, stream>>>(x, xs, W0, b0, W1, b1, W2, b2,
                                               out);
}